// Round 7
// baseline (234.863 us; speedup 1.0000x reference)
//
#include <hip/hip_runtime.h>
#include <hip/hip_bf16.h>

// GCN 2-layer forward. CSR-pull, dinv folded into stored vectors (h1s=h1*dinv,
// h2s=h2*dinv) -> epack is src-only (4 B/edge), weightless gather loops.

#define D1 128

typedef __attribute__((ext_vector_type(8))) short short8;
typedef __attribute__((ext_vector_type(4))) float floatx4;

__device__ __forceinline__ unsigned short f2bf(float f) {
    unsigned u = __float_as_uint(f);
    u += 0x7fff + ((u >> 16) & 1);         // RNE to bf16
    return (unsigned short)(u >> 16);
}
__device__ __forceinline__ float bflo(unsigned u) { return __uint_as_float(u << 16); }
__device__ __forceinline__ float bfhi(unsigned u) { return __uint_as_float(u & 0xffff0000u); }

// ---------------- init: zero cnt + convert W1 -> W1^T bf16 ----------------
__global__ void k_init(const float* __restrict__ W1, unsigned short* __restrict__ W1t,
                       int* __restrict__ cnt, int N) {
    int i = blockIdx.x * 256 + threadIdx.x;
    if (i < N) cnt[i] = 0;
    if (i < D1 * D1) {
        int c = i >> 7, k = i & 127;
        W1t[c * D1 + k] = f2bf(W1[k * D1 + c]);
    }
}

__global__ void k_hist(const int* __restrict__ dst, int* __restrict__ cnt, int E) {
    int e = blockIdx.x * 256 + threadIdx.x;
    if (e < E) atomicAdd(&cnt[dst[e]], 1);
}

// scan over 1024/block; also emits dinv = rsqrt(1+deg)
__global__ __launch_bounds__(256) void k_scan1(const int* __restrict__ cnt,
                                               float* __restrict__ dinv,
                                               int* __restrict__ rowptr,
                                               int* __restrict__ bsum, int N) {
    __shared__ int sd[256];
    int t = threadIdx.x, b = blockIdx.x;
    int base = b * 1024 + t * 4;
    int v[4], tsum = 0;
#pragma unroll
    for (int i = 0; i < 4; ++i) {
        v[i] = (base + i < N) ? cnt[base + i] : 0;
        if (base + i < N) dinv[base + i] = rsqrtf(1.0f + (float)v[i]);
        tsum += v[i];
    }
    sd[t] = tsum;
    __syncthreads();
    for (int off = 1; off < 256; off <<= 1) {
        int x = (t >= off) ? sd[t - off] : 0;
        __syncthreads();
        sd[t] += x;
        __syncthreads();
    }
    int run = sd[t] - tsum;
#pragma unroll
    for (int i = 0; i < 4; ++i) {
        if (base + i < N) rowptr[base + i] = run;
        run += v[i];
    }
    if (t == 255) bsum[b] = sd[255];
}

__global__ void k_scan2(const int* __restrict__ bsum, int* __restrict__ boff, int nb) {
    __shared__ int sd[256];
    int t = threadIdx.x;
    int v = (t < nb) ? bsum[t] : 0;
    sd[t] = v;
    __syncthreads();
    for (int off = 1; off < 256; off <<= 1) {
        int x = (t >= off) ? sd[t - off] : 0;
        __syncthreads();
        sd[t] += x;
        __syncthreads();
    }
    if (t < nb) boff[t] = sd[t] - v;
}

__global__ void k_scan3(int* __restrict__ rowptr, int* __restrict__ cursor,
                        const int* __restrict__ boff, int N, int E) {
    int i = blockIdx.x * 256 + threadIdx.x;
    if (i < N) {
        int r = rowptr[i] + boff[i >> 10];
        rowptr[i] = r;
        cursor[i] = r;
    }
    if (i == 0) rowptr[N] = E;
}

// ---------------- fill: esrc[pos] = src (4 B scatter) ----------------
__global__ void k_fill(const int* __restrict__ src, const int* __restrict__ dst,
                       int* __restrict__ cursor, int* __restrict__ esrc, int E) {
    int e = blockIdx.x * 256 + threadIdx.x;
    if (e >= E) return;
    int pos = atomicAdd(&cursor[dst[e]], 1);
    esrc[pos] = src[e];
}

// ---------------- GEMM1 (MFMA): h1s = (bf16(x) @ bf16(W1)) * dinv[row] ----------------
#define BMM 64
__global__ __launch_bounds__(256) void k_gemm1(
    const float* __restrict__ x, const unsigned short* __restrict__ W1t,
    const float* __restrict__ dinv, unsigned short* __restrict__ h1s, int N)
{
    __shared__ unsigned short Xs[BMM][136];
    __shared__ unsigned short Ws[D1][136];

    const int t = threadIdx.x;
    const int row0 = blockIdx.x * BMM;

#pragma unroll
    for (int i = 0; i < 8; ++i) {
        int idx = t + 256 * i;
        int r = idx >> 4, c8 = idx & 15;
        short8 v = ((const short8*)W1t)[r * 16 + c8];
        *(short8*)&Ws[r][c8 * 8] = v;
    }
#pragma unroll
    for (int i = 0; i < 4; ++i) {
        int idx = t + 256 * i;
        int r = idx >> 4, c8 = idx & 15;
        int row = row0 + r;
        short8 v8 = (short8)0;
        if (row < N) {
            const float* p = x + (size_t)row * D1 + c8 * 8;
            float4 f0 = *(const float4*)p;
            float4 f1 = *(const float4*)(p + 4);
            v8[0] = (short)f2bf(f0.x); v8[1] = (short)f2bf(f0.y);
            v8[2] = (short)f2bf(f0.z); v8[3] = (short)f2bf(f0.w);
            v8[4] = (short)f2bf(f1.x); v8[5] = (short)f2bf(f1.y);
            v8[6] = (short)f2bf(f1.z); v8[7] = (short)f2bf(f1.w);
        }
        *(short8*)&Xs[r][c8 * 8] = v8;
    }
    __syncthreads();

    const int w = t >> 6;
    const int l = t & 63;
    const int m = l & 15;
    const int q = l >> 4;

    floatx4 acc[8];
#pragma unroll
    for (int c = 0; c < 8; ++c) acc[c] = (floatx4)0.0f;

#pragma unroll
    for (int ks = 0; ks < 4; ++ks) {
        short8 a = *(const short8*)&Xs[16 * w + m][ks * 32 + q * 8];
#pragma unroll
        for (int c = 0; c < 8; ++c) {
            short8 b = *(const short8*)&Ws[c * 16 + m][ks * 32 + q * 8];
            acc[c] = __builtin_amdgcn_mfma_f32_16x16x32_bf16(a, b, acc[c], 0, 0, 0);
        }
    }

    // epilogue: scale by dinv[row], store bf16
#pragma unroll
    for (int r = 0; r < 4; ++r) {
        int row = row0 + 16 * w + q * 4 + r;
        if (row >= N) continue;
        float di = dinv[row];
#pragma unroll
        for (int c = 0; c < 8; ++c)
            h1s[(size_t)row * D1 + c * 16 + m] = f2bf(acc[c][r] * di);
    }
}

// ---------------- fused: agg(layer1) + relu + bias + GEMM2 ----------------
// 16 lanes/node, uint4 (8 bf16)/lane, row stride 16 uint4.
// agg_i = dinv_i * (h1s_i + sum_src h1s_src); pure adds in the loop, x4 unroll.
__global__ __launch_bounds__(256) void k_agg1_gemm2(
    const int* __restrict__ rowptr, const int* __restrict__ esrc,
    const float* __restrict__ dinv, const unsigned short* __restrict__ h1s,
    const float* __restrict__ b1, const float* __restrict__ W2,
    float* __restrict__ h2s, int N)
{
    int gid = blockIdx.x * 256 + threadIdx.x;
    int node = gid >> 4;
    if (node >= N) return;
    int lane = gid & 15;

    const uint4* h1v = (const uint4*)h1s;   // 16 uint4 per row

    uint4 u = h1v[(size_t)node * 16 + lane];
    float accA[8], accB[8];
    accA[0] = bflo(u.x); accA[1] = bfhi(u.x);
    accA[2] = bflo(u.y); accA[3] = bfhi(u.y);
    accA[4] = bflo(u.z); accA[5] = bfhi(u.z);
    accA[6] = bflo(u.w); accA[7] = bfhi(u.w);
#pragma unroll
    for (int j = 0; j < 8; ++j) accB[j] = 0.f;

    int beg = rowptr[node], end = rowptr[node + 1];
    int e = beg;
    for (; e + 3 < end; e += 4) {
        int s0 = esrc[e], s1 = esrc[e + 1], s2 = esrc[e + 2], s3 = esrc[e + 3];
        uint4 v0 = h1v[(size_t)s0 * 16 + lane];
        uint4 v1 = h1v[(size_t)s1 * 16 + lane];
        uint4 v2 = h1v[(size_t)s2 * 16 + lane];
        uint4 v3 = h1v[(size_t)s3 * 16 + lane];
        accA[0] += bflo(v0.x); accA[1] += bfhi(v0.x);
        accA[2] += bflo(v0.y); accA[3] += bfhi(v0.y);
        accA[4] += bflo(v0.z); accA[5] += bfhi(v0.z);
        accA[6] += bflo(v0.w); accA[7] += bfhi(v0.w);
        accB[0] += bflo(v1.x); accB[1] += bfhi(v1.x);
        accB[2] += bflo(v1.y); accB[3] += bfhi(v1.y);
        accB[4] += bflo(v1.z); accB[5] += bfhi(v1.z);
        accB[6] += bflo(v1.w); accB[7] += bfhi(v1.w);
        accA[0] += bflo(v2.x); accA[1] += bfhi(v2.x);
        accA[2] += bflo(v2.y); accA[3] += bfhi(v2.y);
        accA[4] += bflo(v2.z); accA[5] += bfhi(v2.z);
        accA[6] += bflo(v2.w); accA[7] += bfhi(v2.w);
        accB[0] += bflo(v3.x); accB[1] += bfhi(v3.x);
        accB[2] += bflo(v3.y); accB[3] += bfhi(v3.y);
        accB[4] += bflo(v3.z); accB[5] += bfhi(v3.z);
        accB[6] += bflo(v3.w); accB[7] += bfhi(v3.w);
    }
    for (; e < end; ++e) {
        uint4 v = h1v[(size_t)esrc[e] * 16 + lane];
        accB[0] += bflo(v.x); accB[1] += bfhi(v.x);
        accB[2] += bflo(v.y); accB[3] += bfhi(v.y);
        accB[4] += bflo(v.z); accB[5] += bfhi(v.z);
        accB[6] += bflo(v.w); accB[7] += bfhi(v.w);
    }

    float di = dinv[node];
    const float4* b1v = (const float4*)b1;
    float4 bbA = b1v[lane * 2 + 0];
    float4 bbB = b1v[lane * 2 + 1];
    float a[8];
    a[0] = fmaxf((accA[0] + accB[0]) * di + bbA.x, 0.f);
    a[1] = fmaxf((accA[1] + accB[1]) * di + bbA.y, 0.f);
    a[2] = fmaxf((accA[2] + accB[2]) * di + bbA.z, 0.f);
    a[3] = fmaxf((accA[3] + accB[3]) * di + bbA.w, 0.f);
    a[4] = fmaxf((accA[4] + accB[4]) * di + bbB.x, 0.f);
    a[5] = fmaxf((accA[5] + accB[5]) * di + bbB.y, 0.f);
    a[6] = fmaxf((accA[6] + accB[6]) * di + bbB.z, 0.f);
    a[7] = fmaxf((accA[7] + accB[7]) * di + bbB.w, 0.f);

    // W2 [128][2]; lane covers rows lane*8..lane*8+7 -> float4 idx lane*4..lane*4+3
    const float4* W2v = (const float4*)W2;
    float p0 = 0.f, p1 = 0.f;
#pragma unroll
    for (int j2 = 0; j2 < 4; ++j2) {
        float4 wv = W2v[lane * 4 + j2];
        p0 += a[j2 * 2] * wv.x + a[j2 * 2 + 1] * wv.z;
        p1 += a[j2 * 2] * wv.y + a[j2 * 2 + 1] * wv.w;
    }

#pragma unroll
    for (int off = 8; off > 0; off >>= 1) {
        p0 += __shfl_xor(p0, off);
        p1 += __shfl_xor(p1, off);
    }
    if (lane == 0) {
        h2s[(size_t)node * 2 + 0] = p0 * di;   // store h2*dinv
        h2s[(size_t)node * 2 + 1] = p1 * di;
    }
}

// ---------------- gather layer 2: out = dinv_i*(h2s_i + sum h2s_src) + b2 ----------------
__global__ void k_gather2(const int* __restrict__ rowptr, const int* __restrict__ esrc,
                          const float* __restrict__ h2s, const float* __restrict__ dinv,
                          const float* __restrict__ b2, float* __restrict__ out, int N)
{
    int i = blockIdx.x * 256 + threadIdx.x;
    if (i >= N) return;
    const float2* h2v = (const float2*)h2s;
    float2 h = h2v[i];
    float o0a = h.x, o1a = h.y;
    float o0b = 0.f, o1b = 0.f;
    int beg = rowptr[i], end = rowptr[i + 1];
    int e = beg;
    for (; e + 3 < end; e += 4) {
        int s0 = esrc[e], s1 = esrc[e + 1], s2 = esrc[e + 2], s3 = esrc[e + 3];
        float2 v0 = h2v[s0];
        float2 v1 = h2v[s1];
        float2 v2 = h2v[s2];
        float2 v3 = h2v[s3];
        o0a += v0.x + v2.x; o1a += v0.y + v2.y;
        o0b += v1.x + v3.x; o1b += v1.y + v3.y;
    }
    for (; e < end; ++e) {
        float2 v = h2v[esrc[e]];
        o0b += v.x; o1b += v.y;
    }
    float di = dinv[i];
    ((float2*)out)[i] = make_float2((o0a + o0b) * di + b2[0], (o1a + o1b) * di + b2[1]);
}

extern "C" void kernel_launch(void* const* d_in, const int* in_sizes, int n_in,
                              void* d_out, int out_size, void* d_ws, size_t ws_size,
                              hipStream_t stream)
{
    const float* x  = (const float*)d_in[0];
    const int*   ei = (const int*)d_in[1];
    const float* W1 = (const float*)d_in[2];
    const float* b1 = (const float*)d_in[3];
    const float* W2 = (const float*)d_in[4];
    const float* b2 = (const float*)d_in[5];
    float* out = (float*)d_out;

    const int N = in_sizes[0] / D1;
    const int E = in_sizes[1] / 2;
    const int* src = ei;
    const int* dst = ei + E;

    char* w = (char*)d_ws;
    auto alloc = [&](size_t bytes) -> char* {
        char* r = w;
        w += (bytes + 15) & ~(size_t)15;
        return r;
    };
    unsigned short* h1s = (unsigned short*)alloc((size_t)N * D1 * 2);
    unsigned short* W1t = (unsigned short*)alloc((size_t)D1 * D1 * 2);
    float* h2s    = (float*)alloc((size_t)N * 2 * 4);
    float* dinv   = (float*)alloc((size_t)N * 4);
    int*   cnt    = (int*)alloc((size_t)N * 4);
    int*   rowptr = (int*)alloc((size_t)(N + 4) * 4);
    int*   bsum   = (int*)alloc(256 * 4);
    int*   boff   = (int*)alloc(256 * 4);
    int*   esrc   = (int*)alloc((size_t)E * 4);

    const int nb = (N + 1023) >> 10;

    k_init <<<(N + 255) / 256, 256, 0, stream>>>(W1, W1t, cnt, N);
    k_hist <<<(E + 255) / 256, 256, 0, stream>>>(dst, cnt, E);
    k_scan1<<<nb, 256, 0, stream>>>(cnt, dinv, rowptr, bsum, N);
    k_scan2<<<1, 256, 0, stream>>>(bsum, boff, nb);
    k_scan3<<<(N + 255) / 256, 256, 0, stream>>>(rowptr, cnt, boff, N, E);
    k_fill <<<(E + 255) / 256, 256, 0, stream>>>(src, dst, cnt, esrc, E);

    k_gemm1<<<(N + BMM - 1) / BMM, 256, 0, stream>>>(x, W1t, dinv, h1s, N);

    k_agg1_gemm2<<<(N * 16 + 255) / 256, 256, 0, stream>>>(rowptr, esrc, dinv, h1s, b1, W2, h2s, N);

    k_gather2<<<(N + 255) / 256, 256, 0, stream>>>(rowptr, esrc, h2s, dinv, b2, out, N);
}

// Round 8
// 229.493 us; speedup vs baseline: 1.0234x; 1.0234x over previous
//
#include <hip/hip_runtime.h>
#include <hip/hip_bf16.h>

// GCN 2-layer forward. CSR-pull, dinv folded into stored vectors, bucketed
// two-pass CSR permutation (kills the cross-XCD scatter write amplification).

#define D1 128
#define BSH 9                 // 512 nodes per bucket
#define BSZ (1 << BSH)
#define CHA 8192              // edges per block in pass A

typedef __attribute__((ext_vector_type(8))) short short8;
typedef __attribute__((ext_vector_type(4))) float floatx4;

__device__ __forceinline__ unsigned short f2bf(float f) {
    unsigned u = __float_as_uint(f);
    u += 0x7fff + ((u >> 16) & 1);         // RNE to bf16
    return (unsigned short)(u >> 16);
}
__device__ __forceinline__ float bflo(unsigned u) { return __uint_as_float(u << 16); }
__device__ __forceinline__ float bfhi(unsigned u) { return __uint_as_float(u & 0xffff0000u); }

// ---------------- init: zero cnt + convert W1 -> W1^T bf16 ----------------
__global__ void k_init(const float* __restrict__ W1, unsigned short* __restrict__ W1t,
                       int* __restrict__ cnt, int N) {
    int i = blockIdx.x * 256 + threadIdx.x;
    if (i < N) cnt[i] = 0;
    if (i < D1 * D1) {
        int c = i >> 7, k = i & 127;
        W1t[c * D1 + k] = f2bf(W1[k * D1 + c]);
    }
}

__global__ void k_hist(const int* __restrict__ dst, int* __restrict__ cnt, int E) {
    int e = blockIdx.x * 256 + threadIdx.x;
    if (e < E) atomicAdd(&cnt[dst[e]], 1);
}

// scan over 1024/block; also emits dinv = rsqrt(1+deg)
__global__ __launch_bounds__(256) void k_scan1(const int* __restrict__ cnt,
                                               float* __restrict__ dinv,
                                               int* __restrict__ rowptr,
                                               int* __restrict__ bsum, int N) {
    __shared__ int sd[256];
    int t = threadIdx.x, b = blockIdx.x;
    int base = b * 1024 + t * 4;
    int v[4], tsum = 0;
#pragma unroll
    for (int i = 0; i < 4; ++i) {
        v[i] = (base + i < N) ? cnt[base + i] : 0;
        if (base + i < N) dinv[base + i] = rsqrtf(1.0f + (float)v[i]);
        tsum += v[i];
    }
    sd[t] = tsum;
    __syncthreads();
    for (int off = 1; off < 256; off <<= 1) {
        int x = (t >= off) ? sd[t - off] : 0;
        __syncthreads();
        sd[t] += x;
        __syncthreads();
    }
    int run = sd[t] - tsum;
#pragma unroll
    for (int i = 0; i < 4; ++i) {
        if (base + i < N) rowptr[base + i] = run;
        run += v[i];
    }
    if (t == 255) bsum[b] = sd[255];
}

__global__ void k_scan2(const int* __restrict__ bsum, int* __restrict__ boff, int nb) {
    __shared__ int sd[256];
    int t = threadIdx.x;
    int v = (t < nb) ? bsum[t] : 0;
    sd[t] = v;
    __syncthreads();
    for (int off = 1; off < 256; off <<= 1) {
        int x = (t >= off) ? sd[t - off] : 0;
        __syncthreads();
        sd[t] += x;
        __syncthreads();
    }
    if (t < nb) boff[t] = sd[t] - v;
}

// finalize rowptr; emit per-bucket write cursors bcur[b] = rowptr[b*512]
__global__ void k_scan3(int* __restrict__ rowptr, const int* __restrict__ boff,
                        int* __restrict__ bcur, int N, int E) {
    int i = blockIdx.x * 256 + threadIdx.x;
    if (i < N) {
        int r = rowptr[i] + boff[i >> 10];
        rowptr[i] = r;
        if ((i & (BSZ - 1)) == 0) bcur[i >> BSH] = r;
    }
    if (i == 0) rowptr[N] = E;
}

// ---------------- pass A: bucket edges by dst>>9, packed = src<<9 | (dst&511) ----
__global__ __launch_bounds__(256) void k_binA(
    const int* __restrict__ src, const int* __restrict__ dst,
    int* __restrict__ bcur, unsigned* __restrict__ packed, int E, int nbuck)
{
    __shared__ int hist[256];
    __shared__ int cur[256];
    const int t = threadIdx.x;
    const int e0 = blockIdx.x * CHA;
    const int e1 = min(e0 + CHA, E);

    for (int i = t; i < nbuck; i += 256) hist[i] = 0;
    __syncthreads();
    for (int i = e0 + t; i < e1; i += 256)
        atomicAdd(&hist[dst[i] >> BSH], 1);
    __syncthreads();
    for (int i = t; i < nbuck; i += 256)
        cur[i] = (hist[i] > 0) ? atomicAdd(&bcur[i], hist[i]) : 0;
    __syncthreads();
    for (int i = e0 + t; i < e1; i += 256) {
        int d = dst[i];
        int b = d >> BSH;
        int pos = atomicAdd(&cur[b], 1);
        packed[pos] = ((unsigned)src[i] << BSH) | (unsigned)(d & (BSZ - 1));
    }
}

// ---------------- pass B: within-bucket placement (single CU per bucket) -------
__global__ __launch_bounds__(256) void k_binB(
    const int* __restrict__ rowptr, const unsigned* __restrict__ packed,
    int* __restrict__ esrc, int N)
{
    __shared__ int lcur[BSZ];
    const int t = threadIdx.x;
    const int s = blockIdx.x << BSH;
    const int en = min(s + BSZ, N);
    const int base = rowptr[s];
    const int cnt = rowptr[en] - base;

    for (int i = t; i < en - s; i += 256) lcur[i] = rowptr[s + i] - base;
    __syncthreads();
    for (int i = t; i < cnt; i += 256) {
        unsigned p = packed[base + i];
        int ld = (int)(p & (BSZ - 1));
        int pos = atomicAdd(&lcur[ld], 1);
        esrc[base + pos] = (int)(p >> BSH);
    }
}

// ---------------- GEMM1 (MFMA): h1s = (bf16(x) @ bf16(W1)) * dinv[row] ----------
#define BMM 64
__global__ __launch_bounds__(256) void k_gemm1(
    const float* __restrict__ x, const unsigned short* __restrict__ W1t,
    const float* __restrict__ dinv, unsigned short* __restrict__ h1s, int N)
{
    __shared__ unsigned short Xs[BMM][136];
    __shared__ unsigned short Ws[D1][136];

    const int t = threadIdx.x;
    const int row0 = blockIdx.x * BMM;

#pragma unroll
    for (int i = 0; i < 8; ++i) {
        int idx = t + 256 * i;
        int r = idx >> 4, c8 = idx & 15;
        short8 v = ((const short8*)W1t)[r * 16 + c8];
        *(short8*)&Ws[r][c8 * 8] = v;
    }
#pragma unroll
    for (int i = 0; i < 4; ++i) {
        int idx = t + 256 * i;
        int r = idx >> 4, c8 = idx & 15;
        int row = row0 + r;
        short8 v8 = (short8)0;
        if (row < N) {
            const float* p = x + (size_t)row * D1 + c8 * 8;
            float4 f0 = *(const float4*)p;
            float4 f1 = *(const float4*)(p + 4);
            v8[0] = (short)f2bf(f0.x); v8[1] = (short)f2bf(f0.y);
            v8[2] = (short)f2bf(f0.z); v8[3] = (short)f2bf(f0.w);
            v8[4] = (short)f2bf(f1.x); v8[5] = (short)f2bf(f1.y);
            v8[6] = (short)f2bf(f1.z); v8[7] = (short)f2bf(f1.w);
        }
        *(short8*)&Xs[r][c8 * 8] = v8;
    }
    __syncthreads();

    const int w = t >> 6;
    const int l = t & 63;
    const int m = l & 15;
    const int q = l >> 4;

    floatx4 acc[8];
#pragma unroll
    for (int c = 0; c < 8; ++c) acc[c] = (floatx4)0.0f;

#pragma unroll
    for (int ks = 0; ks < 4; ++ks) {
        short8 a = *(const short8*)&Xs[16 * w + m][ks * 32 + q * 8];
#pragma unroll
        for (int c = 0; c < 8; ++c) {
            short8 b = *(const short8*)&Ws[c * 16 + m][ks * 32 + q * 8];
            acc[c] = __builtin_amdgcn_mfma_f32_16x16x32_bf16(a, b, acc[c], 0, 0, 0);
        }
    }

#pragma unroll
    for (int r = 0; r < 4; ++r) {
        int row = row0 + 16 * w + q * 4 + r;
        if (row >= N) continue;
        float di = dinv[row];
#pragma unroll
        for (int c = 0; c < 8; ++c)
            h1s[(size_t)row * D1 + c * 16 + m] = f2bf(acc[c][r] * di);
    }
}

// ---------------- fused: agg(layer1) + relu + bias + GEMM2 ----------------
__global__ __launch_bounds__(256) void k_agg1_gemm2(
    const int* __restrict__ rowptr, const int* __restrict__ esrc,
    const float* __restrict__ dinv, const unsigned short* __restrict__ h1s,
    const float* __restrict__ b1, const float* __restrict__ W2,
    float* __restrict__ h2s, int N)
{
    int gid = blockIdx.x * 256 + threadIdx.x;
    int node = gid >> 4;
    if (node >= N) return;
    int lane = gid & 15;

    const uint4* h1v = (const uint4*)h1s;   // 16 uint4 per row

    uint4 u = h1v[(size_t)node * 16 + lane];
    float accA[8], accB[8];
    accA[0] = bflo(u.x); accA[1] = bfhi(u.x);
    accA[2] = bflo(u.y); accA[3] = bfhi(u.y);
    accA[4] = bflo(u.z); accA[5] = bfhi(u.z);
    accA[6] = bflo(u.w); accA[7] = bfhi(u.w);
#pragma unroll
    for (int j = 0; j < 8; ++j) accB[j] = 0.f;

    int beg = rowptr[node], end = rowptr[node + 1];
    int e = beg;
    for (; e + 3 < end; e += 4) {
        int s0 = esrc[e], s1 = esrc[e + 1], s2 = esrc[e + 2], s3 = esrc[e + 3];
        uint4 v0 = h1v[(size_t)s0 * 16 + lane];
        uint4 v1 = h1v[(size_t)s1 * 16 + lane];
        uint4 v2 = h1v[(size_t)s2 * 16 + lane];
        uint4 v3 = h1v[(size_t)s3 * 16 + lane];
        accA[0] += bflo(v0.x); accA[1] += bfhi(v0.x);
        accA[2] += bflo(v0.y); accA[3] += bfhi(v0.y);
        accA[4] += bflo(v0.z); accA[5] += bfhi(v0.z);
        accA[6] += bflo(v0.w); accA[7] += bfhi(v0.w);
        accB[0] += bflo(v1.x); accB[1] += bfhi(v1.x);
        accB[2] += bflo(v1.y); accB[3] += bfhi(v1.y);
        accB[4] += bflo(v1.z); accB[5] += bfhi(v1.z);
        accB[6] += bflo(v1.w); accB[7] += bfhi(v1.w);
        accA[0] += bflo(v2.x); accA[1] += bfhi(v2.x);
        accA[2] += bflo(v2.y); accA[3] += bfhi(v2.y);
        accA[4] += bflo(v2.z); accA[5] += bfhi(v2.z);
        accA[6] += bflo(v2.w); accA[7] += bfhi(v2.w);
        accB[0] += bflo(v3.x); accB[1] += bfhi(v3.x);
        accB[2] += bflo(v3.y); accB[3] += bfhi(v3.y);
        accB[4] += bflo(v3.z); accB[5] += bfhi(v3.z);
        accB[6] += bflo(v3.w); accB[7] += bfhi(v3.w);
    }
    for (; e < end; ++e) {
        uint4 v = h1v[(size_t)esrc[e] * 16 + lane];
        accB[0] += bflo(v.x); accB[1] += bfhi(v.x);
        accB[2] += bflo(v.y); accB[3] += bfhi(v.y);
        accB[4] += bflo(v.z); accB[5] += bfhi(v.z);
        accB[6] += bflo(v.w); accB[7] += bfhi(v.w);
    }

    float di = dinv[node];
    const float4* b1v = (const float4*)b1;
    float4 bbA = b1v[lane * 2 + 0];
    float4 bbB = b1v[lane * 2 + 1];
    float a[8];
    a[0] = fmaxf((accA[0] + accB[0]) * di + bbA.x, 0.f);
    a[1] = fmaxf((accA[1] + accB[1]) * di + bbA.y, 0.f);
    a[2] = fmaxf((accA[2] + accB[2]) * di + bbA.z, 0.f);
    a[3] = fmaxf((accA[3] + accB[3]) * di + bbA.w, 0.f);
    a[4] = fmaxf((accA[4] + accB[4]) * di + bbB.x, 0.f);
    a[5] = fmaxf((accA[5] + accB[5]) * di + bbB.y, 0.f);
    a[6] = fmaxf((accA[6] + accB[6]) * di + bbB.z, 0.f);
    a[7] = fmaxf((accA[7] + accB[7]) * di + bbB.w, 0.f);

    const float4* W2v = (const float4*)W2;
    float p0 = 0.f, p1 = 0.f;
#pragma unroll
    for (int j2 = 0; j2 < 4; ++j2) {
        float4 wv = W2v[lane * 4 + j2];
        p0 += a[j2 * 2] * wv.x + a[j2 * 2 + 1] * wv.z;
        p1 += a[j2 * 2] * wv.y + a[j2 * 2 + 1] * wv.w;
    }

#pragma unroll
    for (int off = 8; off > 0; off >>= 1) {
        p0 += __shfl_xor(p0, off);
        p1 += __shfl_xor(p1, off);
    }
    if (lane == 0) {
        h2s[(size_t)node * 2 + 0] = p0 * di;   // store h2*dinv
        h2s[(size_t)node * 2 + 1] = p1 * di;
    }
}

// ---------------- gather layer 2: out = dinv_i*(h2s_i + sum h2s_src) + b2 -------
__global__ void k_gather2(const int* __restrict__ rowptr, const int* __restrict__ esrc,
                          const float* __restrict__ h2s, const float* __restrict__ dinv,
                          const float* __restrict__ b2, float* __restrict__ out, int N)
{
    int i = blockIdx.x * 256 + threadIdx.x;
    if (i >= N) return;
    const float2* h2v = (const float2*)h2s;
    float2 h = h2v[i];
    float o0a = h.x, o1a = h.y;
    float o0b = 0.f, o1b = 0.f;
    int beg = rowptr[i], end = rowptr[i + 1];
    int e = beg;
    for (; e + 3 < end; e += 4) {
        int s0 = esrc[e], s1 = esrc[e + 1], s2 = esrc[e + 2], s3 = esrc[e + 3];
        float2 v0 = h2v[s0];
        float2 v1 = h2v[s1];
        float2 v2 = h2v[s2];
        float2 v3 = h2v[s3];
        o0a += v0.x + v2.x; o1a += v0.y + v2.y;
        o0b += v1.x + v3.x; o1b += v1.y + v3.y;
    }
    for (; e < end; ++e) {
        float2 v = h2v[esrc[e]];
        o0b += v.x; o1b += v.y;
    }
    float di = dinv[i];
    ((float2*)out)[i] = make_float2((o0a + o0b) * di + b2[0], (o1a + o1b) * di + b2[1]);
}

extern "C" void kernel_launch(void* const* d_in, const int* in_sizes, int n_in,
                              void* d_out, int out_size, void* d_ws, size_t ws_size,
                              hipStream_t stream)
{
    const float* x  = (const float*)d_in[0];
    const int*   ei = (const int*)d_in[1];
    const float* W1 = (const float*)d_in[2];
    const float* b1 = (const float*)d_in[3];
    const float* W2 = (const float*)d_in[4];
    const float* b2 = (const float*)d_in[5];
    float* out = (float*)d_out;

    const int N = in_sizes[0] / D1;
    const int E = in_sizes[1] / 2;
    const int* src = ei;
    const int* dst = ei + E;

    char* w = (char*)d_ws;
    auto alloc = [&](size_t bytes) -> char* {
        char* r = w;
        w += (bytes + 15) & ~(size_t)15;
        return r;
    };
    unsigned short* h1s = (unsigned short*)alloc((size_t)N * D1 * 2);
    unsigned short* W1t = (unsigned short*)alloc((size_t)D1 * D1 * 2);
    float* h2s    = (float*)alloc((size_t)N * 2 * 4);
    float* dinv   = (float*)alloc((size_t)N * 4);
    int*   cnt    = (int*)alloc((size_t)N * 4);
    int*   rowptr = (int*)alloc((size_t)(N + 4) * 4);
    int*   bsum   = (int*)alloc(256 * 4);
    int*   boff   = (int*)alloc(256 * 4);
    int*   bcur   = (int*)alloc(256 * 4);
    unsigned* packed = (unsigned*)alloc((size_t)E * 4);
    int*   esrc   = (int*)alloc((size_t)E * 4);

    const int nb    = (N + 1023) >> 10;
    const int nbuck = (N + BSZ - 1) >> BSH;

    k_init <<<(N + 255) / 256, 256, 0, stream>>>(W1, W1t, cnt, N);
    k_hist <<<(E + 255) / 256, 256, 0, stream>>>(dst, cnt, E);
    k_scan1<<<nb, 256, 0, stream>>>(cnt, dinv, rowptr, bsum, N);
    k_scan2<<<1, 256, 0, stream>>>(bsum, boff, nb);
    k_scan3<<<(N + 255) / 256, 256, 0, stream>>>(rowptr, boff, bcur, N, E);
    k_binA <<<(E + CHA - 1) / CHA, 256, 0, stream>>>(src, dst, bcur, packed, E, nbuck);
    k_binB <<<nbuck, 256, 0, stream>>>(rowptr, packed, esrc, N);

    k_gemm1<<<(N + BMM - 1) / BMM, 256, 0, stream>>>(x, W1t, dinv, h1s, N);

    k_agg1_gemm2<<<(N * 16 + 255) / 256, 256, 0, stream>>>(rowptr, esrc, dinv, h1s, b1, W2, h2s, N);

    k_gather2<<<(N + 255) / 256, 256, 0, stream>>>(rowptr, esrc, h2s, dinv, b2, out, N);
}

// Round 9
// 199.145 us; speedup vs baseline: 1.1794x; 1.1524x over previous
//
#include <hip/hip_runtime.h>
#include <hip/hip_bf16.h>

// GCN 2-layer forward. Bucketed CSR build (per-bucket LDS hist/scan in binB,
// no global node histogram), degree-sorted node schedule for divergence-free agg.

#define D1 128
#define BSH 9                 // 512 nodes per bucket
#define BSZ (1 << BSH)
#define CHA 4096              // edges per block in pass A

typedef __attribute__((ext_vector_type(8))) short short8;
typedef __attribute__((ext_vector_type(4))) float floatx4;

__device__ __forceinline__ unsigned short f2bf(float f) {
    unsigned u = __float_as_uint(f);
    u += 0x7fff + ((u >> 16) & 1);         // RNE to bf16
    return (unsigned short)(u >> 16);
}
__device__ __forceinline__ float bflo(unsigned u) { return __uint_as_float(u << 16); }
__device__ __forceinline__ float bfhi(unsigned u) { return __uint_as_float(u & 0xffff0000u); }

// ---------------- init: zero bucket counts + convert W1 -> W1^T bf16 ----------------
__global__ void k_init(const float* __restrict__ W1, unsigned short* __restrict__ W1t,
                       int* __restrict__ bcount) {
    int i = blockIdx.x * 256 + threadIdx.x;
    if (i < 256) bcount[i] = 0;
    if (i < D1 * D1) {
        int c = i >> 7, k = i & 127;
        W1t[c * D1 + k] = f2bf(W1[k * D1 + c]);
    }
}

// ---------------- bucket-level histogram (196 bins) ----------------
__global__ __launch_bounds__(256) void k_bcount(const int* __restrict__ dst,
                                                int* __restrict__ bcount,
                                                int E, int nbuck) {
    __shared__ int h[256];
    int t = threadIdx.x;
    h[t] = 0;
    __syncthreads();
    for (int i = blockIdx.x * 256 + t; i < E; i += gridDim.x * 256)
        atomicAdd(&h[dst[i] >> BSH], 1);
    __syncthreads();
    if (t < nbuck && h[t]) atomicAdd(&bcount[t], h[t]);
}

// ---------------- 1-block scan of bucket counts -> bbase, bcur ----------------
__global__ __launch_bounds__(256) void k_bscan(const int* __restrict__ bcount,
                                               int* __restrict__ bbase,
                                               int* __restrict__ bcur,
                                               int* __restrict__ rowptr,
                                               int nbuck, int N, int E) {
    __shared__ int sd[256];
    int t = threadIdx.x;
    int v = (t < nbuck) ? bcount[t] : 0;
    sd[t] = v;
    __syncthreads();
    for (int off = 1; off < 256; off <<= 1) {
        int x = (t >= off) ? sd[t - off] : 0;
        __syncthreads();
        sd[t] += x;
        __syncthreads();
    }
    int excl = sd[t] - v;
    if (t <= nbuck) bbase[t] = (t < nbuck) ? excl : E;
    if (t < nbuck) bcur[t] = excl;
    if (t == 0) {
        bbase[nbuck] = E;
        rowptr[N] = E;
    }
}

// ---------------- pass A: bucket edges, packed = src<<9 | (dst&511) ----------------
__global__ __launch_bounds__(256) void k_binA(
    const int* __restrict__ src, const int* __restrict__ dst,
    int* __restrict__ bcur, unsigned* __restrict__ packed, int E, int nbuck)
{
    __shared__ int hist[256];
    __shared__ int cur[256];
    const int t = threadIdx.x;
    const int e0 = blockIdx.x * CHA;
    const int e1 = min(e0 + CHA, E);

    for (int i = t; i < nbuck; i += 256) hist[i] = 0;
    __syncthreads();
    for (int i = e0 + t; i < e1; i += 256)
        atomicAdd(&hist[dst[i] >> BSH], 1);
    __syncthreads();
    for (int i = t; i < nbuck; i += 256)
        cur[i] = (hist[i] > 0) ? atomicAdd(&bcur[i], hist[i]) : 0;
    __syncthreads();
    for (int i = e0 + t; i < e1; i += 256) {
        int d = dst[i];
        int b = d >> BSH;
        int pos = atomicAdd(&cur[b], 1);
        packed[pos] = ((unsigned)src[i] << BSH) | (unsigned)(d & (BSZ - 1));
    }
}

// ---------------- pass B: per-bucket node hist + scan + rowptr/dinv + esrc
//                  + degree-sorted schedule (order) ----------------
__global__ __launch_bounds__(512) void k_binB(
    const int* __restrict__ bbase, const unsigned* __restrict__ packed,
    int* __restrict__ rowptr, float* __restrict__ dinv,
    int* __restrict__ esrc, int* __restrict__ order, int N)
{
    __shared__ int lh[BSZ];     // local degree
    __shared__ int sd[BSZ];     // scan workspace
    __shared__ int lcur[BSZ];   // placement cursors
    __shared__ int dbin[64];    // degree histogram (clamped)
    __shared__ int dcur[64];

    const int t = threadIdx.x;
    const int s = blockIdx.x << BSH;
    const int n = min(BSZ, N - s);
    const int base = bbase[blockIdx.x];
    const int cnt = bbase[blockIdx.x + 1] - base;

    lh[t] = 0;
    if (t < 64) dbin[t] = 0;
    __syncthreads();
    for (int i = t; i < cnt; i += 512)
        atomicAdd(&lh[packed[base + i] & (BSZ - 1)], 1);
    __syncthreads();

    // inclusive scan over 512
    sd[t] = lh[t];
    __syncthreads();
    for (int off = 1; off < BSZ; off <<= 1) {
        int x = (t >= off) ? sd[t - off] : 0;
        __syncthreads();
        sd[t] += x;
        __syncthreads();
    }
    int excl = sd[t] - lh[t];
    if (t < n) {
        rowptr[s + t] = base + excl;
        dinv[s + t] = rsqrtf(1.0f + (float)lh[t]);
        atomicAdd(&dbin[min(lh[t], 63)], 1);
    }
    lcur[t] = excl;
    __syncthreads();

    // place esrc within bucket window
    for (int i = t; i < cnt; i += 512) {
        unsigned p = packed[base + i];
        int ld = (int)(p & (BSZ - 1));
        int pos = atomicAdd(&lcur[ld], 1);
        esrc[base + pos] = (int)(p >> BSH);
    }

    // degree counting-sort -> order (schedule permutation)
    __syncthreads();
    if (t < 64) sd[t] = dbin[t];
    __syncthreads();
    for (int off = 1; off < 64; off <<= 1) {
        int x = (t >= off && t < 64) ? sd[t - off] : 0;
        __syncthreads();
        if (t < 64) sd[t] += x;
        __syncthreads();
    }
    if (t < 64) dcur[t] = sd[t] - dbin[t];
    __syncthreads();
    if (t < n) {
        int b = min(lh[t], 63);
        int pos = atomicAdd(&dcur[b], 1);
        order[s + pos] = s + t;
    }
}

// ---------------- GEMM1 (MFMA): h1s = (bf16(x) @ bf16(W1)) * dinv[row] ----------
#define BMM 64
__global__ __launch_bounds__(256) void k_gemm1(
    const float* __restrict__ x, const unsigned short* __restrict__ W1t,
    const float* __restrict__ dinv, unsigned short* __restrict__ h1s, int N)
{
    __shared__ unsigned short Xs[BMM][136];
    __shared__ unsigned short Ws[D1][136];

    const int t = threadIdx.x;
    const int row0 = blockIdx.x * BMM;

#pragma unroll
    for (int i = 0; i < 8; ++i) {
        int idx = t + 256 * i;
        int r = idx >> 4, c8 = idx & 15;
        short8 v = ((const short8*)W1t)[r * 16 + c8];
        *(short8*)&Ws[r][c8 * 8] = v;
    }
#pragma unroll
    for (int i = 0; i < 4; ++i) {
        int idx = t + 256 * i;
        int r = idx >> 4, c8 = idx & 15;
        int row = row0 + r;
        short8 v8 = (short8)0;
        if (row < N) {
            const float* p = x + (size_t)row * D1 + c8 * 8;
            float4 f0 = *(const float4*)p;
            float4 f1 = *(const float4*)(p + 4);
            v8[0] = (short)f2bf(f0.x); v8[1] = (short)f2bf(f0.y);
            v8[2] = (short)f2bf(f0.z); v8[3] = (short)f2bf(f0.w);
            v8[4] = (short)f2bf(f1.x); v8[5] = (short)f2bf(f1.y);
            v8[6] = (short)f2bf(f1.z); v8[7] = (short)f2bf(f1.w);
        }
        *(short8*)&Xs[r][c8 * 8] = v8;
    }
    __syncthreads();

    const int w = t >> 6;
    const int l = t & 63;
    const int m = l & 15;
    const int q = l >> 4;

    floatx4 acc[8];
#pragma unroll
    for (int c = 0; c < 8; ++c) acc[c] = (floatx4)0.0f;

#pragma unroll
    for (int ks = 0; ks < 4; ++ks) {
        short8 a = *(const short8*)&Xs[16 * w + m][ks * 32 + q * 8];
#pragma unroll
        for (int c = 0; c < 8; ++c) {
            short8 b = *(const short8*)&Ws[c * 16 + m][ks * 32 + q * 8];
            acc[c] = __builtin_amdgcn_mfma_f32_16x16x32_bf16(a, b, acc[c], 0, 0, 0);
        }
    }

#pragma unroll
    for (int r = 0; r < 4; ++r) {
        int row = row0 + 16 * w + q * 4 + r;
        if (row >= N) continue;
        float di = dinv[row];
#pragma unroll
        for (int c = 0; c < 8; ++c)
            h1s[(size_t)row * D1 + c * 16 + m] = f2bf(acc[c][r] * di);
    }
}

// ---------------- fused: agg(layer1) + relu + bias + GEMM2, degree-sorted ------
__global__ __launch_bounds__(256) void k_agg1_gemm2(
    const int* __restrict__ rowptr, const int* __restrict__ esrc,
    const int* __restrict__ order,
    const float* __restrict__ dinv, const unsigned short* __restrict__ h1s,
    const float* __restrict__ b1, const float* __restrict__ W2,
    float* __restrict__ h2s, int N)
{
    int gid = blockIdx.x * 256 + threadIdx.x;
    int grp = gid >> 4;
    if (grp >= N) return;
    int node = order[grp];
    int lane = gid & 15;

    const uint4* h1v = (const uint4*)h1s;   // 16 uint4 per row

    uint4 u = h1v[(size_t)node * 16 + lane];
    float accA[8], accB[8];
    accA[0] = bflo(u.x); accA[1] = bfhi(u.x);
    accA[2] = bflo(u.y); accA[3] = bfhi(u.y);
    accA[4] = bflo(u.z); accA[5] = bfhi(u.z);
    accA[6] = bflo(u.w); accA[7] = bfhi(u.w);
#pragma unroll
    for (int j = 0; j < 8; ++j) accB[j] = 0.f;

    int beg = rowptr[node], end = rowptr[node + 1];
    int e = beg;
    for (; e + 3 < end; e += 4) {
        int s0 = esrc[e], s1 = esrc[e + 1], s2 = esrc[e + 2], s3 = esrc[e + 3];
        uint4 v0 = h1v[(size_t)s0 * 16 + lane];
        uint4 v1 = h1v[(size_t)s1 * 16 + lane];
        uint4 v2 = h1v[(size_t)s2 * 16 + lane];
        uint4 v3 = h1v[(size_t)s3 * 16 + lane];
        accA[0] += bflo(v0.x); accA[1] += bfhi(v0.x);
        accA[2] += bflo(v0.y); accA[3] += bfhi(v0.y);
        accA[4] += bflo(v0.z); accA[5] += bfhi(v0.z);
        accA[6] += bflo(v0.w); accA[7] += bfhi(v0.w);
        accB[0] += bflo(v1.x); accB[1] += bfhi(v1.x);
        accB[2] += bflo(v1.y); accB[3] += bfhi(v1.y);
        accB[4] += bflo(v1.z); accB[5] += bfhi(v1.z);
        accB[6] += bflo(v1.w); accB[7] += bfhi(v1.w);
        accA[0] += bflo(v2.x); accA[1] += bfhi(v2.x);
        accA[2] += bflo(v2.y); accA[3] += bfhi(v2.y);
        accA[4] += bflo(v2.z); accA[5] += bfhi(v2.z);
        accA[6] += bflo(v2.w); accA[7] += bfhi(v2.w);
        accB[0] += bflo(v3.x); accB[1] += bfhi(v3.x);
        accB[2] += bflo(v3.y); accB[3] += bfhi(v3.y);
        accB[4] += bflo(v3.z); accB[5] += bfhi(v3.z);
        accB[6] += bflo(v3.w); accB[7] += bfhi(v3.w);
    }
    for (; e < end; ++e) {
        uint4 v = h1v[(size_t)esrc[e] * 16 + lane];
        accB[0] += bflo(v.x); accB[1] += bfhi(v.x);
        accB[2] += bflo(v.y); accB[3] += bfhi(v.y);
        accB[4] += bflo(v.z); accB[5] += bfhi(v.z);
        accB[6] += bflo(v.w); accB[7] += bfhi(v.w);
    }

    float di = dinv[node];
    const float4* b1v = (const float4*)b1;
    float4 bbA = b1v[lane * 2 + 0];
    float4 bbB = b1v[lane * 2 + 1];
    float a[8];
    a[0] = fmaxf((accA[0] + accB[0]) * di + bbA.x, 0.f);
    a[1] = fmaxf((accA[1] + accB[1]) * di + bbA.y, 0.f);
    a[2] = fmaxf((accA[2] + accB[2]) * di + bbA.z, 0.f);
    a[3] = fmaxf((accA[3] + accB[3]) * di + bbA.w, 0.f);
    a[4] = fmaxf((accA[4] + accB[4]) * di + bbB.x, 0.f);
    a[5] = fmaxf((accA[5] + accB[5]) * di + bbB.y, 0.f);
    a[6] = fmaxf((accA[6] + accB[6]) * di + bbB.z, 0.f);
    a[7] = fmaxf((accA[7] + accB[7]) * di + bbB.w, 0.f);

    const float4* W2v = (const float4*)W2;
    float p0 = 0.f, p1 = 0.f;
#pragma unroll
    for (int j2 = 0; j2 < 4; ++j2) {
        float4 wv = W2v[lane * 4 + j2];
        p0 += a[j2 * 2] * wv.x + a[j2 * 2 + 1] * wv.z;
        p1 += a[j2 * 2] * wv.y + a[j2 * 2 + 1] * wv.w;
    }

#pragma unroll
    for (int off = 8; off > 0; off >>= 1) {
        p0 += __shfl_xor(p0, off);
        p1 += __shfl_xor(p1, off);
    }
    if (lane == 0) {
        h2s[(size_t)node * 2 + 0] = p0 * di;   // store h2*dinv
        h2s[(size_t)node * 2 + 1] = p1 * di;
    }
}

// ---------------- gather layer 2: out = dinv_i*(h2s_i + sum h2s_src) + b2 -------
__global__ void k_gather2(const int* __restrict__ rowptr, const int* __restrict__ esrc,
                          const float* __restrict__ h2s, const float* __restrict__ dinv,
                          const float* __restrict__ b2, float* __restrict__ out, int N)
{
    int i = blockIdx.x * 256 + threadIdx.x;
    if (i >= N) return;
    const float2* h2v = (const float2*)h2s;
    float2 h = h2v[i];
    float o0a = h.x, o1a = h.y;
    float o0b = 0.f, o1b = 0.f;
    int beg = rowptr[i], end = rowptr[i + 1];
    int e = beg;
    for (; e + 3 < end; e += 4) {
        int s0 = esrc[e], s1 = esrc[e + 1], s2 = esrc[e + 2], s3 = esrc[e + 3];
        float2 v0 = h2v[s0];
        float2 v1 = h2v[s1];
        float2 v2 = h2v[s2];
        float2 v3 = h2v[s3];
        o0a += v0.x + v2.x; o1a += v0.y + v2.y;
        o0b += v1.x + v3.x; o1b += v1.y + v3.y;
    }
    for (; e < end; ++e) {
        float2 v = h2v[esrc[e]];
        o0b += v.x; o1b += v.y;
    }
    float di = dinv[i];
    ((float2*)out)[i] = make_float2((o0a + o0b) * di + b2[0], (o1a + o1b) * di + b2[1]);
}

extern "C" void kernel_launch(void* const* d_in, const int* in_sizes, int n_in,
                              void* d_out, int out_size, void* d_ws, size_t ws_size,
                              hipStream_t stream)
{
    const float* x  = (const float*)d_in[0];
    const int*   ei = (const int*)d_in[1];
    const float* W1 = (const float*)d_in[2];
    const float* b1 = (const float*)d_in[3];
    const float* W2 = (const float*)d_in[4];
    const float* b2 = (const float*)d_in[5];
    float* out = (float*)d_out;

    const int N = in_sizes[0] / D1;
    const int E = in_sizes[1] / 2;
    const int* src = ei;
    const int* dst = ei + E;

    char* w = (char*)d_ws;
    auto alloc = [&](size_t bytes) -> char* {
        char* r = w;
        w += (bytes + 15) & ~(size_t)15;
        return r;
    };
    unsigned short* h1s = (unsigned short*)alloc((size_t)N * D1 * 2);
    unsigned short* W1t = (unsigned short*)alloc((size_t)D1 * D1 * 2);
    float* h2s    = (float*)alloc((size_t)N * 2 * 4);
    float* dinv   = (float*)alloc((size_t)N * 4);
    int*   rowptr = (int*)alloc((size_t)(N + 4) * 4);
    int*   order  = (int*)alloc((size_t)N * 4);
    int*   bcount = (int*)alloc(256 * 4);
    int*   bbase  = (int*)alloc(260 * 4);
    int*   bcur   = (int*)alloc(256 * 4);
    unsigned* packed = (unsigned*)alloc((size_t)E * 4);
    int*   esrc   = (int*)alloc((size_t)E * 4);

    const int nbuck = (N + BSZ - 1) >> BSH;

    k_init  <<<(D1 * D1 + 255) / 256, 256, 0, stream>>>(W1, W1t, bcount);
    k_bcount<<<256, 256, 0, stream>>>(dst, bcount, E, nbuck);
    k_bscan <<<1, 256, 0, stream>>>(bcount, bbase, bcur, rowptr, nbuck, N, E);
    k_binA  <<<(E + CHA - 1) / CHA, 256, 0, stream>>>(src, dst, bcur, packed, E, nbuck);
    k_binB  <<<nbuck, 512, 0, stream>>>(bbase, packed, rowptr, dinv, esrc, order, N);

    k_gemm1<<<(N + BMM - 1) / BMM, 256, 0, stream>>>(x, W1t, dinv, h1s, N);

    k_agg1_gemm2<<<(N * 16 + 255) / 256, 256, 0, stream>>>(rowptr, esrc, order, dinv, h1s, b1, W2, h2s, N);

    k_gather2<<<(N + 255) / 256, 256, 0, stream>>>(rowptr, esrc, h2s, dinv, b2, out, N);
}